// Round 1
// baseline (226.783 us; speedup 1.0000x reference)
//
#include <hip/hip_runtime.h>
#include <hip/hip_bf16.h>

// GraphConvolution: out = (adj_agg o (X @ W)) + bias  restructured as
//   out = X @ W' + bias,  W'[k,r] = sum_{e: rows[e]==r} vals[e] * W[k, cols[e]]
// (aggregation acts on W's column dim -> commutes with the GEMM).
// N=2048, D_IN=1024, D_OUT=8192, E=131072.

#define N_ROWS 2048
#define D_IN   1024
#define D_OUT  8192

typedef __attribute__((ext_vector_type(8))) short bf16x8;
typedef __attribute__((ext_vector_type(4))) float f32x4;

__device__ __forceinline__ float bf2f(unsigned short u) {
    union { unsigned int i; float f; } x; x.i = ((unsigned int)u) << 16; return x.f;
}
__device__ __forceinline__ unsigned short f2bf(float f) {
    union { unsigned int i; float f; } x; x.f = f;
    unsigned int r = x.i + 0x7FFFu + ((x.i >> 16) & 1u);   // round-nearest-even
    return (unsigned short)(r >> 16);
}

// async global->LDS, 16B per lane; LDS dest = wave-uniform base + lane*16
__device__ __forceinline__ void async_load16(const void* g, void* l) {
    __builtin_amdgcn_global_load_lds(
        (const __attribute__((address_space(1))) void*)g,
        (__attribute__((address_space(3))) void*)l,
        16, 0, 0);
}

// ---------------- stage 1: W [D_IN, D_OUT] f32 -> W^T [D_OUT, D_IN] bf16 ----
__global__ __launch_bounds__(256) void transpose_convert(
    const float* __restrict__ w, unsigned short* __restrict__ wt)
{
    __shared__ float tile[32][33];
    const int bx = blockIdx.x;          // D_OUT/32 = 256
    const int by = blockIdx.y;          // D_IN/32  = 32
    const int tx = threadIdx.x & 31;
    const int ty = threadIdx.x >> 5;    // 0..7
    #pragma unroll
    for (int j = 0; j < 32; j += 8)
        tile[ty + j][tx] = w[(size_t)(by * 32 + ty + j) * D_OUT + bx * 32 + tx];
    __syncthreads();
    #pragma unroll
    for (int j = 0; j < 32; j += 8)
        wt[(size_t)(bx * 32 + ty + j) * D_IN + by * 32 + tx] = f2bf(tile[tx][ty + j]);
}

// ---------------- stage 2: X f32 -> bf16 ------------------------------------
__global__ __launch_bounds__(256) void convert_input(
    const float* __restrict__ in, unsigned short* __restrict__ out)
{
    const int i = (blockIdx.x * 256 + threadIdx.x) * 4;   // sizes divide exactly
    const float4 v = *(const float4*)(in + i);
    ushort4 o; o.x = f2bf(v.x); o.y = f2bf(v.y); o.z = f2bf(v.z); o.w = f2bf(v.w);
    *(ushort4*)(out + i) = o;
}

// ---------------- stage 3: CSR build ----------------------------------------
__global__ void count_rows(const int* __restrict__ rows, int* counts, int E) {
    int e = blockIdx.x * blockDim.x + threadIdx.x;
    if (e < E) atomicAdd(&counts[rows[e]], 1);
}

__global__ __launch_bounds__(1024) void scan_8192(
    const int* __restrict__ counts, int* __restrict__ offsets)
{
    __shared__ int part[1024];
    const int t = threadIdx.x;
    int loc[8];
    int s = 0;
    #pragma unroll
    for (int j = 0; j < 8; ++j) { loc[j] = s; s += counts[t * 8 + j]; }
    part[t] = s;
    __syncthreads();
    for (int off = 1; off < 1024; off <<= 1) {
        int v = (t >= off) ? part[t - off] : 0;
        __syncthreads();
        part[t] += v;
        __syncthreads();
    }
    const int base = (t == 0) ? 0 : part[t - 1];
    #pragma unroll
    for (int j = 0; j < 8; ++j) offsets[t * 8 + j] = base + loc[j];
    if (t == 1023) offsets[8192] = part[1023];
}

__global__ void fill_csr(const int* __restrict__ rows, const int* __restrict__ offsets,
                         int* cursors, int* eids, int E) {
    int e = blockIdx.x * blockDim.x + threadIdx.x;
    if (e < E) {
        int r = rows[e];
        int pos = atomicAdd(&cursors[r], 1);
        eids[offsets[r] + pos] = e;
    }
}

// ---------------- stage 4: W'^T[r,:] = sum vals[e] * W^T[cols[e],:] ---------
__global__ __launch_bounds__(256) void aggregate_rows(
    const unsigned short* __restrict__ wtb,   // W^T [D_OUT, D_IN] bf16
    const int* __restrict__ offsets,
    const int* __restrict__ eids,
    const int* __restrict__ cols,
    const float* __restrict__ vals,
    unsigned short* __restrict__ wpt)         // W'^T [D_OUT, D_IN] bf16
{
    const int r = blockIdx.x;        // 8192
    const int t = threadIdx.x;       // 256, each handles 4 k's
    const int beg = offsets[r], end = offsets[r + 1];
    float a0 = 0.f, a1 = 0.f, a2 = 0.f, a3 = 0.f;
    for (int i = beg; i < end; ++i) {
        const int e = eids[i];
        const int c = cols[e];
        const float v = vals[e];
        const ushort4 w = *(const ushort4*)&wtb[(size_t)c * D_IN + t * 4];
        a0 += v * bf2f(w.x);
        a1 += v * bf2f(w.y);
        a2 += v * bf2f(w.z);
        a3 += v * bf2f(w.w);
    }
    ushort4 o; o.x = f2bf(a0); o.y = f2bf(a1); o.z = f2bf(a2); o.w = f2bf(a3);
    *(ushort4*)&wpt[(size_t)r * D_IN + t * 4] = o;
}

// ---------------- stage 5: C = A @ B^T + bias (m97 structure) ---------------
// A [N_ROWS, D_IN] bf16, B [D_OUT, D_IN] bf16 (= W'^T), C [N_ROWS, D_OUT] f32.
// 128x128 tile, BK=32, 4 waves in 2x2, each wave 4x4 of 16x16x32 MFMA.
__global__ __launch_bounds__(256) void gemm_bt_bias(
    const unsigned short* __restrict__ A,
    const unsigned short* __restrict__ B,
    const float*  __restrict__ bias,
    float* __restrict__ C)
{
    __shared__ unsigned short As[128 * 32];
    __shared__ unsigned short Bs[128 * 32];

    const int tid  = threadIdx.x;
    const int wave = tid >> 6;
    const int lane = tid & 63;
    const int quad = lane >> 4;
    const int l16  = lane & 15;
    const int wr   = wave >> 1;    // 0..1  (A rows)
    const int wc   = wave & 1;     // 0..1  (B rows = out cols)

    const int bc = blockIdx.x;     // 0..63  col-chunk (r)
    const int br = blockIdx.y;     // 0..15  row-chunk (n)

    // staging map: wave stages tile bytes [wave*2048, wave*2048+2048)
    const int so0 = wave * 2048 + lane * 16;
    const int so1 = so0 + 1024;
    const int ar0 = so0 >> 6, ac0 = so0 & 63;   // tile row / byte-in-row
    const int ar1 = so1 >> 6, ac1 = so1 & 63;

    const char* Ab = (const char*)A + (size_t)(br * 128) * (D_IN * 2);
    const char* Bb = (const char*)B + (size_t)(bc * 128) * (D_IN * 2);
    char* AsB = (char*)As;
    char* BsB = (char*)Bs;

    f32x4 acc[4][4];
    #pragma unroll
    for (int i = 0; i < 4; ++i)
        #pragma unroll
        for (int j = 0; j < 4; ++j)
            acc[i][j] = (f32x4){0.f, 0.f, 0.f, 0.f};

    const unsigned short* apb = As + (wr * 64 + l16) * 32 + quad * 8;
    const unsigned short* bpb = Bs + (wc * 64 + l16) * 32 + quad * 8;

    for (int it = 0; it < D_IN / 32; ++it) {
        __syncthreads();                       // prior compute done before overwrite
        const int kb = it * 64;                // byte offset along k
        async_load16(Ab + (size_t)ar0 * (D_IN * 2) + kb + ac0, AsB + so0);
        async_load16(Ab + (size_t)ar1 * (D_IN * 2) + kb + ac1, AsB + so1);
        async_load16(Bb + (size_t)ar0 * (D_IN * 2) + kb + ac0, BsB + so0);
        async_load16(Bb + (size_t)ar1 * (D_IN * 2) + kb + ac1, BsB + so1);
        __syncthreads();                       // compiler drains vmcnt(0) here

        bf16x8 af[4], bf[4];
        #pragma unroll
        for (int mi = 0; mi < 4; ++mi)
            af[mi] = *(const bf16x8*)(apb + mi * 16 * 32);
        #pragma unroll
        for (int ni = 0; ni < 4; ++ni)
            bf[ni] = *(const bf16x8*)(bpb + ni * 16 * 32);
        #pragma unroll
        for (int mi = 0; mi < 4; ++mi)
            #pragma unroll
            for (int ni = 0; ni < 4; ++ni)
                acc[mi][ni] = __builtin_amdgcn_mfma_f32_16x16x32_bf16(
                    af[mi], bf[ni], acc[mi][ni], 0, 0, 0);
    }

    // epilogue: C/D layout col=lane&15, row=quad*4+reg  (m89-verified)
    #pragma unroll
    for (int ni = 0; ni < 4; ++ni) {
        const int col = bc * 128 + wc * 64 + ni * 16 + l16;
        const float bv = bias[col];
        #pragma unroll
        for (int mi = 0; mi < 4; ++mi) {
            const int row0 = br * 128 + wr * 64 + mi * 16 + quad * 4;
            #pragma unroll
            for (int r = 0; r < 4; ++r)
                C[(size_t)(row0 + r) * D_OUT + col] = acc[mi][ni][r] + bv;
        }
    }
}

extern "C" void kernel_launch(void* const* d_in, const int* in_sizes, int n_in,
                              void* d_out, int out_size, void* d_ws, size_t ws_size,
                              hipStream_t stream) {
    (void)n_in; (void)out_size; (void)ws_size;
    const float* input    = (const float*)d_in[0];   // [2048,1024]
    const float* weight   = (const float*)d_in[1];   // [1024,8192]
    const float* bias     = (const float*)d_in[2];   // [8192]
    const int*   adj_rows = (const int*)d_in[3];     // [E]
    const int*   adj_cols = (const int*)d_in[4];     // [E]
    const float* adj_vals = (const float*)d_in[5];   // [E]
    const int E = in_sizes[3];

    // workspace layout (~38.5 MB; ws re-poisoned each call, everything below
    // is fully rewritten or explicitly zeroed every launch)
    char* ws = (char*)d_ws;
    unsigned short* wtb = (unsigned short*)ws;                                // 16 MB  W^T bf16
    unsigned short* wpt = (unsigned short*)(ws + (size_t)16 * 1024 * 1024);   // 16 MB  W'^T bf16
    unsigned short* abf = (unsigned short*)(ws + (size_t)32 * 1024 * 1024);   //  4 MB  X bf16
    int* counts  = (int*)(ws + (size_t)36 * 1024 * 1024);                     // 32 KB
    int* cursors = counts + D_OUT;                                            // 32 KB
    int* offsets = cursors + D_OUT;                                           // 32 KB + 4
    int* eids    = offsets + (D_OUT + 1);                                     // 512 KB

    hipMemsetAsync(counts, 0, 2 * D_OUT * sizeof(int), stream);  // counts + cursors
    transpose_convert<<<dim3(D_OUT / 32, D_IN / 32), 256, 0, stream>>>(weight, wtb);
    convert_input<<<(N_ROWS * D_IN) / 1024, 256, 0, stream>>>(input, abf);
    count_rows<<<(E + 255) / 256, 256, 0, stream>>>(adj_rows, counts, E);
    scan_8192<<<1, 1024, 0, stream>>>(counts, offsets);
    fill_csr<<<(E + 255) / 256, 256, 0, stream>>>(adj_rows, offsets, cursors, eids, E);
    aggregate_rows<<<D_OUT, 256, 0, stream>>>(wtb, offsets, eids, adj_cols, adj_vals, wpt);
    gemm_bt_bias<<<dim3(D_OUT / 128, N_ROWS / 128), 256, 0, stream>>>(
        abf, wpt, bias, (float*)d_out);
}

// Round 2
// 223.323 us; speedup vs baseline: 1.0155x; 1.0155x over previous
//
#include <hip/hip_runtime.h>
#include <hip/hip_bf16.h>

// GraphConvolution: out = (adj_agg o (X @ W)) + bias  restructured as
//   out = X @ W' + bias,  W'[k,r] = sum_{e: rows[e]==r} vals[e] * W[k, cols[e]]
// (aggregation acts on W's column dim -> commutes with the GEMM).
// N=2048, D_IN=1024, D_OUT=8192, E=131072.

#define N_ROWS 2048
#define D_IN   1024
#define D_OUT  8192

typedef __attribute__((ext_vector_type(8))) short bf16x8;
typedef __attribute__((ext_vector_type(4))) float f32x4;

__device__ __forceinline__ float bf2f(unsigned short u) {
    union { unsigned int i; float f; } x; x.i = ((unsigned int)u) << 16; return x.f;
}
__device__ __forceinline__ unsigned short f2bf(float f) {
    union { unsigned int i; float f; } x; x.f = f;
    unsigned int r = x.i + 0x7FFFu + ((x.i >> 16) & 1u);   // round-nearest-even
    return (unsigned short)(r >> 16);
}

// async global->LDS, 16B per lane; LDS dest = wave-uniform base + lane*16
__device__ __forceinline__ void async_load16(const void* g, void* l) {
    __builtin_amdgcn_global_load_lds(
        (const __attribute__((address_space(1))) void*)g,
        (__attribute__((address_space(3))) void*)l,
        16, 0, 0);
}

// ---------------- stage 1: W [D_IN, D_OUT] f32 -> W^T [D_OUT, D_IN] bf16 ----
__global__ __launch_bounds__(256) void transpose_convert(
    const float* __restrict__ w, unsigned short* __restrict__ wt)
{
    __shared__ float tile[32][33];
    const int bx = blockIdx.x;          // D_OUT/32 = 256
    const int by = blockIdx.y;          // D_IN/32  = 32
    const int tx = threadIdx.x & 31;
    const int ty = threadIdx.x >> 5;    // 0..7
    #pragma unroll
    for (int j = 0; j < 32; j += 8)
        tile[ty + j][tx] = w[(size_t)(by * 32 + ty + j) * D_OUT + bx * 32 + tx];
    __syncthreads();
    #pragma unroll
    for (int j = 0; j < 32; j += 8)
        wt[(size_t)(bx * 32 + ty + j) * D_IN + by * 32 + tx] = f2bf(tile[tx][ty + j]);
}

// ---------------- stage 2: X f32 -> bf16 ------------------------------------
__global__ __launch_bounds__(256) void convert_input(
    const float* __restrict__ in, unsigned short* __restrict__ out)
{
    const int i = (blockIdx.x * 256 + threadIdx.x) * 4;   // sizes divide exactly
    const float4 v = *(const float4*)(in + i);
    ushort4 o; o.x = f2bf(v.x); o.y = f2bf(v.y); o.z = f2bf(v.z); o.w = f2bf(v.w);
    *(ushort4*)(out + i) = o;
}

// ---------------- stage 3: CSR build ----------------------------------------
__global__ void count_rows(const int* __restrict__ rows, int* counts, int E) {
    int e = blockIdx.x * blockDim.x + threadIdx.x;
    if (e < E) atomicAdd(&counts[rows[e]], 1);
}

__global__ __launch_bounds__(1024) void scan_8192(
    const int* __restrict__ counts, int* __restrict__ offsets)
{
    __shared__ int part[1024];
    const int t = threadIdx.x;
    int loc[8];
    int s = 0;
    #pragma unroll
    for (int j = 0; j < 8; ++j) { loc[j] = s; s += counts[t * 8 + j]; }
    part[t] = s;
    __syncthreads();
    for (int off = 1; off < 1024; off <<= 1) {
        int v = (t >= off) ? part[t - off] : 0;
        __syncthreads();
        part[t] += v;
        __syncthreads();
    }
    const int base = (t == 0) ? 0 : part[t - 1];
    #pragma unroll
    for (int j = 0; j < 8; ++j) offsets[t * 8 + j] = base + loc[j];
    if (t == 1023) offsets[8192] = part[1023];
}

// store cols/vals directly in CSR order (kills the eids indirection)
__global__ void fill_csr(const int* __restrict__ rows, const int* __restrict__ cols,
                         const float* __restrict__ vals, const int* __restrict__ offsets,
                         int* cursors, int* __restrict__ csr_cols,
                         float* __restrict__ csr_vals, int E) {
    int e = blockIdx.x * blockDim.x + threadIdx.x;
    if (e < E) {
        int r = rows[e];
        int pos = atomicAdd(&cursors[r], 1);
        int d = offsets[r] + pos;
        csr_cols[d] = cols[e];
        csr_vals[d] = vals[e];
    }
}

// ---------------- stage 4: W'^T[r,:] = sum vals[e] * W^T[cols[e],:] ---------
// k split into 8 chunks of 128; gridDim.x=8 (fastest-varying) so chunk kc
// round-robins onto XCD kc -> per-XCD gather working set = 8192x128 bf16
// = 2 MB, L2-resident. 4 waves/block, one row per wave.
__global__ __launch_bounds__(256) void aggregate_rows(
    const unsigned short* __restrict__ wtb,   // W^T [D_OUT, D_IN] bf16
    const int* __restrict__ offsets,
    const int* __restrict__ csr_cols,
    const float* __restrict__ csr_vals,
    unsigned short* __restrict__ wpt)         // W'^T [D_OUT, D_IN] bf16
{
    const int kc   = blockIdx.x;              // 0..7  k-chunk (XCD affinity)
    const int wave = threadIdx.x >> 6;
    const int lane = threadIdx.x & 63;
    const int r    = blockIdx.y * 4 + wave;   // row handled by this wave
    const int k0   = kc * 128 + lane * 2;

    const int beg = offsets[r], end = offsets[r + 1];
    float a0 = 0.f, a1 = 0.f, b0 = 0.f, b1 = 0.f;
    int i = beg;
    for (; i + 2 <= end; i += 2) {            // 2 independent gathers in flight
        const int   c0 = csr_cols[i];
        const int   c1 = csr_cols[i + 1];
        const float v0 = csr_vals[i];
        const float v1 = csr_vals[i + 1];
        const ushort2 w0 = *(const ushort2*)&wtb[(size_t)c0 * D_IN + k0];
        const ushort2 w1 = *(const ushort2*)&wtb[(size_t)c1 * D_IN + k0];
        a0 += v0 * bf2f(w0.x); a1 += v0 * bf2f(w0.y);
        b0 += v1 * bf2f(w1.x); b1 += v1 * bf2f(w1.y);
    }
    if (i < end) {
        const int c = csr_cols[i];
        const float v = csr_vals[i];
        const ushort2 w = *(const ushort2*)&wtb[(size_t)c * D_IN + k0];
        a0 += v * bf2f(w.x); a1 += v * bf2f(w.y);
    }
    ushort2 o; o.x = f2bf(a0 + b0); o.y = f2bf(a1 + b1);
    *(ushort2*)&wpt[(size_t)r * D_IN + k0] = o;
}

// ---------------- stage 5: C = A @ B^T + bias (m97 structure) ---------------
// A [N_ROWS, D_IN] bf16, B [D_OUT, D_IN] bf16 (= W'^T), C [N_ROWS, D_OUT] f32.
// 128x128 tile, BK=32, 4 waves in 2x2, each wave 4x4 of 16x16x32 MFMA.
__global__ __launch_bounds__(256) void gemm_bt_bias(
    const unsigned short* __restrict__ A,
    const unsigned short* __restrict__ B,
    const float*  __restrict__ bias,
    float* __restrict__ C)
{
    __shared__ unsigned short As[128 * 32];
    __shared__ unsigned short Bs[128 * 32];

    const int tid  = threadIdx.x;
    const int wave = tid >> 6;
    const int lane = tid & 63;
    const int quad = lane >> 4;
    const int l16  = lane & 15;
    const int wr   = wave >> 1;    // 0..1  (A rows)
    const int wc   = wave & 1;     // 0..1  (B rows = out cols)

    const int bc = blockIdx.x;     // 0..63  col-chunk (r)
    const int br = blockIdx.y;     // 0..15  row-chunk (n)

    // staging map: wave stages tile bytes [wave*2048, wave*2048+2048)
    const int so0 = wave * 2048 + lane * 16;
    const int so1 = so0 + 1024;
    const int ar0 = so0 >> 6, ac0 = so0 & 63;   // tile row / byte-in-row
    const int ar1 = so1 >> 6, ac1 = so1 & 63;

    const char* Ab = (const char*)A + (size_t)(br * 128) * (D_IN * 2);
    const char* Bb = (const char*)B + (size_t)(bc * 128) * (D_IN * 2);
    char* AsB = (char*)As;
    char* BsB = (char*)Bs;

    f32x4 acc[4][4];
    #pragma unroll
    for (int i = 0; i < 4; ++i)
        #pragma unroll
        for (int j = 0; j < 4; ++j)
            acc[i][j] = (f32x4){0.f, 0.f, 0.f, 0.f};

    const unsigned short* apb = As + (wr * 64 + l16) * 32 + quad * 8;
    const unsigned short* bpb = Bs + (wc * 64 + l16) * 32 + quad * 8;

    for (int it = 0; it < D_IN / 32; ++it) {
        __syncthreads();                       // prior compute done before overwrite
        const int kb = it * 64;                // byte offset along k
        async_load16(Ab + (size_t)ar0 * (D_IN * 2) + kb + ac0, AsB + so0);
        async_load16(Ab + (size_t)ar1 * (D_IN * 2) + kb + ac1, AsB + so1);
        async_load16(Bb + (size_t)ar0 * (D_IN * 2) + kb + ac0, BsB + so0);
        async_load16(Bb + (size_t)ar1 * (D_IN * 2) + kb + ac1, BsB + so1);
        __syncthreads();                       // compiler drains vmcnt(0) here

        bf16x8 af[4], bf[4];
        #pragma unroll
        for (int mi = 0; mi < 4; ++mi)
            af[mi] = *(const bf16x8*)(apb + mi * 16 * 32);
        #pragma unroll
        for (int ni = 0; ni < 4; ++ni)
            bf[ni] = *(const bf16x8*)(bpb + ni * 16 * 32);
        #pragma unroll
        for (int mi = 0; mi < 4; ++mi)
            #pragma unroll
            for (int ni = 0; ni < 4; ++ni)
                acc[mi][ni] = __builtin_amdgcn_mfma_f32_16x16x32_bf16(
                    af[mi], bf[ni], acc[mi][ni], 0, 0, 0);
    }

    // epilogue: C/D layout col=lane&15, row=quad*4+reg  (m89-verified)
    #pragma unroll
    for (int ni = 0; ni < 4; ++ni) {
        const int col = bc * 128 + wc * 64 + ni * 16 + l16;
        const float bv = bias[col];
        #pragma unroll
        for (int mi = 0; mi < 4; ++mi) {
            const int row0 = br * 128 + wr * 64 + mi * 16 + quad * 4;
            #pragma unroll
            for (int r = 0; r < 4; ++r)
                C[(size_t)(row0 + r) * D_OUT + col] = acc[mi][ni][r] + bv;
        }
    }
}

extern "C" void kernel_launch(void* const* d_in, const int* in_sizes, int n_in,
                              void* d_out, int out_size, void* d_ws, size_t ws_size,
                              hipStream_t stream) {
    (void)n_in; (void)out_size; (void)ws_size;
    const float* input    = (const float*)d_in[0];   // [2048,1024]
    const float* weight   = (const float*)d_in[1];   // [1024,8192]
    const float* bias     = (const float*)d_in[2];   // [8192]
    const int*   adj_rows = (const int*)d_in[3];     // [E]
    const int*   adj_cols = (const int*)d_in[4];     // [E]
    const float* adj_vals = (const float*)d_in[5];   // [E]
    const int E = in_sizes[3];

    // workspace layout (~37.6 MB; ws re-poisoned each call, everything below
    // is fully rewritten or explicitly zeroed every launch)
    char* ws = (char*)d_ws;
    unsigned short* wtb = (unsigned short*)ws;                                // 16 MB  W^T bf16
    unsigned short* wpt = (unsigned short*)(ws + (size_t)16 * 1024 * 1024);   // 16 MB  W'^T bf16
    unsigned short* abf = (unsigned short*)(ws + (size_t)32 * 1024 * 1024);   //  4 MB  X bf16
    int*   counts   = (int*)(ws + (size_t)36 * 1024 * 1024);                  // 32 KB
    int*   cursors  = counts + D_OUT;                                         // 32 KB
    int*   offsets  = cursors + D_OUT;                                        // 32 KB + 4
    int*   csr_cols = offsets + (D_OUT + 1);                                  // 512 KB
    float* csr_vals = (float*)(csr_cols + 131072);                            // 512 KB

    hipMemsetAsync(counts, 0, 2 * D_OUT * sizeof(int), stream);  // counts + cursors
    transpose_convert<<<dim3(D_OUT / 32, D_IN / 32), 256, 0, stream>>>(weight, wtb);
    convert_input<<<(N_ROWS * D_IN) / 1024, 256, 0, stream>>>(input, abf);
    count_rows<<<(E + 255) / 256, 256, 0, stream>>>(adj_rows, counts, E);
    scan_8192<<<1, 1024, 0, stream>>>(counts, offsets);
    fill_csr<<<(E + 255) / 256, 256, 0, stream>>>(adj_rows, adj_cols, adj_vals,
                                                  offsets, cursors, csr_cols, csr_vals, E);
    aggregate_rows<<<dim3(8, D_OUT / 4), 256, 0, stream>>>(
        wtb, offsets, csr_cols, csr_vals, wpt);
    gemm_bt_bias<<<dim3(D_OUT / 128, N_ROWS / 128), 256, 0, stream>>>(
        abf, wpt, bias, (float*)d_out);
}

// Round 3
// 205.649 us; speedup vs baseline: 1.1028x; 1.0859x over previous
//
#include <hip/hip_runtime.h>
#include <hip/hip_bf16.h>

// GraphConvolution: out = (adj_agg o (X @ W)) + bias  restructured as
//   out = X @ W' + bias,  W'[k,r] = sum_{e: rows[e]==r} vals[e] * W[k, cols[e]]
// (aggregation acts on W's column dim -> commutes with the GEMM).
// N=2048, D_IN=1024, D_OUT=8192, E=131072.

#define N_ROWS 2048
#define D_IN   1024
#define D_OUT  8192

typedef __attribute__((ext_vector_type(8))) short bf16x8;
typedef __attribute__((ext_vector_type(4))) float f32x4;

__device__ __forceinline__ float bf2f(unsigned short u) {
    union { unsigned int i; float f; } x; x.i = ((unsigned int)u) << 16; return x.f;
}
__device__ __forceinline__ unsigned short f2bf(float f) {
    union { unsigned int i; float f; } x; x.f = f;
    unsigned int r = x.i + 0x7FFFu + ((x.i >> 16) & 1u);   // round-nearest-even
    return (unsigned short)(r >> 16);
}

// async global->LDS, 16B per lane; LDS dest = wave-uniform base + lane*16
__device__ __forceinline__ void async_load16(const void* g, void* l) {
    __builtin_amdgcn_global_load_lds(
        (const __attribute__((address_space(1))) void*)g,
        (__attribute__((address_space(3))) void*)l,
        16, 0, 0);
}

// ---------------- stage 1: W [D_IN, D_OUT] f32 -> W^T [D_OUT, D_IN] bf16 ----
__global__ __launch_bounds__(256) void transpose_convert(
    const float* __restrict__ w, unsigned short* __restrict__ wt)
{
    __shared__ float tile[32][33];
    const int bx = blockIdx.x;          // D_OUT/32 = 256
    const int by = blockIdx.y;          // D_IN/32  = 32
    const int tx = threadIdx.x & 31;
    const int ty = threadIdx.x >> 5;    // 0..7
    #pragma unroll
    for (int j = 0; j < 32; j += 8)
        tile[ty + j][tx] = w[(size_t)(by * 32 + ty + j) * D_OUT + bx * 32 + tx];
    __syncthreads();
    #pragma unroll
    for (int j = 0; j < 32; j += 8)
        wt[(size_t)(bx * 32 + ty + j) * D_IN + by * 32 + tx] = f2bf(tile[tx][ty + j]);
}

// ---------------- stage 2: X f32 -> bf16 ------------------------------------
__global__ __launch_bounds__(256) void convert_input(
    const float* __restrict__ in, unsigned short* __restrict__ out)
{
    const int i = (blockIdx.x * 256 + threadIdx.x) * 4;   // sizes divide exactly
    const float4 v = *(const float4*)(in + i);
    ushort4 o; o.x = f2bf(v.x); o.y = f2bf(v.y); o.z = f2bf(v.z); o.w = f2bf(v.w);
    *(ushort4*)(out + i) = o;
}

// ---------------- stage 3: CSR build ----------------------------------------
__global__ void count_rows(const int* __restrict__ rows, int* counts, int E) {
    int e = blockIdx.x * blockDim.x + threadIdx.x;
    if (e < E) atomicAdd(&counts[rows[e]], 1);
}

__global__ __launch_bounds__(1024) void scan_8192(
    const int* __restrict__ counts, int* __restrict__ offsets)
{
    __shared__ int part[1024];
    const int t = threadIdx.x;
    int loc[8];
    int s = 0;
    #pragma unroll
    for (int j = 0; j < 8; ++j) { loc[j] = s; s += counts[t * 8 + j]; }
    part[t] = s;
    __syncthreads();
    for (int off = 1; off < 1024; off <<= 1) {
        int v = (t >= off) ? part[t - off] : 0;
        __syncthreads();
        part[t] += v;
        __syncthreads();
    }
    const int base = (t == 0) ? 0 : part[t - 1];
    #pragma unroll
    for (int j = 0; j < 8; ++j) offsets[t * 8 + j] = base + loc[j];
    if (t == 1023) offsets[8192] = part[1023];
}

// store cols/vals directly in CSR order (kills the eids indirection)
__global__ void fill_csr(const int* __restrict__ rows, const int* __restrict__ cols,
                         const float* __restrict__ vals, const int* __restrict__ offsets,
                         int* cursors, int* __restrict__ csr_cols,
                         float* __restrict__ csr_vals, int E) {
    int e = blockIdx.x * blockDim.x + threadIdx.x;
    if (e < E) {
        int r = rows[e];
        int pos = atomicAdd(&cursors[r], 1);
        int d = offsets[r] + pos;
        csr_cols[d] = cols[e];
        csr_vals[d] = vals[e];
    }
}

// ---------------- stage 4: W'^T[r,:] = sum vals[e] * W^T[cols[e],:] ---------
// TEMPORAL k-chunk locality: grid (2048 row-groups, 8 kc), x fastest-varying.
// All 2048 blocks of chunk kc (= exactly one machine-load of 8192 waves)
// dispatch before chunk kc+1, so the live gather working set at any moment
// is one 8192x128 bf16 slice = 2 MB -> resident in every XCD's 4 MB L2.
// No XCD-mapping assumption (R2's spatial %8 trick measurably failed).
__global__ __launch_bounds__(256) void aggregate_rows(
    const unsigned short* __restrict__ wtb,   // W^T [D_OUT, D_IN] bf16
    const int* __restrict__ offsets,
    const int* __restrict__ csr_cols,
    const float* __restrict__ csr_vals,
    unsigned short* __restrict__ wpt)         // W'^T [D_OUT, D_IN] bf16
{
    const int kc   = blockIdx.y;              // 0..7  k-chunk (slow dim)
    const int wave = threadIdx.x >> 6;
    const int lane = threadIdx.x & 63;
    const int r    = blockIdx.x * 4 + wave;   // row handled by this wave
    const int k0   = kc * 128 + lane * 2;

    const int beg = offsets[r], end = offsets[r + 1];
    float a0 = 0.f, a1 = 0.f, b0 = 0.f, b1 = 0.f;
    float c0 = 0.f, c1 = 0.f, d0 = 0.f, d1 = 0.f;
    int i = beg;
    for (; i + 4 <= end; i += 4) {            // 4 independent gathers in flight
        const int   e0 = csr_cols[i],     e1 = csr_cols[i + 1];
        const int   e2 = csr_cols[i + 2], e3 = csr_cols[i + 3];
        const float v0 = csr_vals[i],     v1 = csr_vals[i + 1];
        const float v2 = csr_vals[i + 2], v3 = csr_vals[i + 3];
        const ushort2 w0 = *(const ushort2*)&wtb[(size_t)e0 * D_IN + k0];
        const ushort2 w1 = *(const ushort2*)&wtb[(size_t)e1 * D_IN + k0];
        const ushort2 w2 = *(const ushort2*)&wtb[(size_t)e2 * D_IN + k0];
        const ushort2 w3 = *(const ushort2*)&wtb[(size_t)e3 * D_IN + k0];
        a0 += v0 * bf2f(w0.x); a1 += v0 * bf2f(w0.y);
        b0 += v1 * bf2f(w1.x); b1 += v1 * bf2f(w1.y);
        c0 += v2 * bf2f(w2.x); c1 += v2 * bf2f(w2.y);
        d0 += v3 * bf2f(w3.x); d1 += v3 * bf2f(w3.y);
    }
    for (; i < end; ++i) {
        const int c = csr_cols[i];
        const float v = csr_vals[i];
        const ushort2 w = *(const ushort2*)&wtb[(size_t)c * D_IN + k0];
        a0 += v * bf2f(w.x); a1 += v * bf2f(w.y);
    }
    ushort2 o; o.x = f2bf((a0 + b0) + (c0 + d0)); o.y = f2bf((a1 + b1) + (c1 + d1));
    *(ushort2*)&wpt[(size_t)r * D_IN + k0] = o;
}

// ---------------- stage 5: C = A @ B^T + bias -------------------------------
// A [N_ROWS, D_IN] bf16, B [D_OUT, D_IN] bf16 (= W'^T), C [N_ROWS, D_OUT] f32.
// 128x128 tile, BK=64 (16 iters, 32 MFMA/wave per barrier pair), 4 waves 2x2.
// LDS rows are 128 B (8 chunks of 16 B); chunk c of row r stored at physical
// chunk c ^ (r & 7)  -> fragment reads spread 16 lanes over all 8 chunk-slots
// (2-way aliasing = free, m136), killing R2's 8-way conflicts (4.19M).
__global__ __launch_bounds__(256, 4) void gemm_bt_bias(
    const unsigned short* __restrict__ A,
    const unsigned short* __restrict__ B,
    const float*  __restrict__ bias,
    float* __restrict__ C)
{
    __shared__ unsigned short As[128 * 64];   // 16 KB
    __shared__ unsigned short Bs[128 * 64];   // 16 KB

    const int tid  = threadIdx.x;
    const int wave = tid >> 6;
    const int lane = tid & 63;
    const int quad = lane >> 4;
    const int l16  = lane & 15;
    const int wr   = wave >> 1;    // 0..1  (A rows)
    const int wc   = wave & 1;     // 0..1  (B rows = out cols)

    const int bc = blockIdx.x;     // 0..63  col-chunk (r)
    const int br = blockIdx.y;     // 0..15  row-chunk (n)

    // staging map: thread stages 4 A-chunks + 4 B-chunks of 16 B per iter.
    // LDS chunk index ci = wave*256 + round*64 + lane; row = ci/8,
    // physical chunk = lane&7, logical chunk = (lane&7) ^ ((lane>>3)&7).
    const int lrow = lane >> 3;              // 0..7 row-within-octet
    const int lchk = (lane & 7) ^ lrow;      // logical (source) chunk
    const int ldsb = wave * 4096 + lane * 16;   // byte base in LDS region

    const char* Ab = (const char*)A + (size_t)(br * 128) * (D_IN * 2);
    const char* Bb = (const char*)B + (size_t)(bc * 128) * (D_IN * 2);
    char* AsB = (char*)As;
    char* BsB = (char*)Bs;

    f32x4 acc[4][4];
    #pragma unroll
    for (int i = 0; i < 4; ++i)
        #pragma unroll
        for (int j = 0; j < 4; ++j)
            acc[i][j] = (f32x4){0.f, 0.f, 0.f, 0.f};

    // fragment read pointers (shorts): row = wr*64 + mi*16 + l16 (row&7 = l16&7),
    // phys chunk for k-step s: (s*4 + quad) ^ (l16 & 7)
    const int x0 = quad ^ (l16 & 7);
    const unsigned short* apb0 = As + (wr * 64 + l16) * 64 + x0 * 8;
    const unsigned short* apb1 = As + (wr * 64 + l16) * 64 + (x0 ^ 4) * 8;
    const unsigned short* bpb0 = Bs + (wc * 64 + l16) * 64 + x0 * 8;
    const unsigned short* bpb1 = Bs + (wc * 64 + l16) * 64 + (x0 ^ 4) * 8;

    for (int it = 0; it < D_IN / 64; ++it) {
        __syncthreads();                       // prior compute done before overwrite
        const int kb = it * 128;               // byte offset along k
        #pragma unroll
        for (int round = 0; round < 4; ++round) {
            const int row = wave * 32 + round * 8 + lrow;
            async_load16(Ab + (size_t)row * (D_IN * 2) + kb + lchk * 16,
                         AsB + ldsb + round * 1024);
            async_load16(Bb + (size_t)row * (D_IN * 2) + kb + lchk * 16,
                         BsB + ldsb + round * 1024);
        }
        __syncthreads();                       // compiler drains vmcnt(0) here

        #pragma unroll
        for (int s = 0; s < 2; ++s) {
            const unsigned short* ap = s ? apb1 : apb0;
            const unsigned short* bp = s ? bpb1 : bpb0;
            bf16x8 af[4], bf[4];
            #pragma unroll
            for (int mi = 0; mi < 4; ++mi)
                af[mi] = *(const bf16x8*)(ap + mi * 16 * 64);
            #pragma unroll
            for (int ni = 0; ni < 4; ++ni)
                bf[ni] = *(const bf16x8*)(bp + ni * 16 * 64);
            #pragma unroll
            for (int mi = 0; mi < 4; ++mi)
                #pragma unroll
                for (int ni = 0; ni < 4; ++ni)
                    acc[mi][ni] = __builtin_amdgcn_mfma_f32_16x16x32_bf16(
                        af[mi], bf[ni], acc[mi][ni], 0, 0, 0);
        }
    }

    // epilogue: C/D layout col=lane&15, row=quad*4+reg  (m89-verified)
    #pragma unroll
    for (int ni = 0; ni < 4; ++ni) {
        const int col = bc * 128 + wc * 64 + ni * 16 + l16;
        const float bv = bias[col];
        #pragma unroll
        for (int mi = 0; mi < 4; ++mi) {
            const int row0 = br * 128 + wr * 64 + mi * 16 + quad * 4;
            #pragma unroll
            for (int r = 0; r < 4; ++r)
                C[(size_t)(row0 + r) * D_OUT + col] = acc[mi][ni][r] + bv;
        }
    }
}

extern "C" void kernel_launch(void* const* d_in, const int* in_sizes, int n_in,
                              void* d_out, int out_size, void* d_ws, size_t ws_size,
                              hipStream_t stream) {
    (void)n_in; (void)out_size; (void)ws_size;
    const float* input    = (const float*)d_in[0];   // [2048,1024]
    const float* weight   = (const float*)d_in[1];   // [1024,8192]
    const float* bias     = (const float*)d_in[2];   // [8192]
    const int*   adj_rows = (const int*)d_in[3];     // [E]
    const int*   adj_cols = (const int*)d_in[4];     // [E]
    const float* adj_vals = (const float*)d_in[5];   // [E]
    const int E = in_sizes[3];

    // workspace layout (~37.6 MB; ws re-poisoned each call, everything below
    // is fully rewritten or explicitly zeroed every launch)
    char* ws = (char*)d_ws;
    unsigned short* wtb = (unsigned short*)ws;                                // 16 MB  W^T bf16
    unsigned short* wpt = (unsigned short*)(ws + (size_t)16 * 1024 * 1024);   // 16 MB  W'^T bf16
    unsigned short* abf = (unsigned short*)(ws + (size_t)32 * 1024 * 1024);   //  4 MB  X bf16
    int*   counts   = (int*)(ws + (size_t)36 * 1024 * 1024);                  // 32 KB
    int*   cursors  = counts + D_OUT;                                         // 32 KB
    int*   offsets  = cursors + D_OUT;                                        // 32 KB + 4
    int*   csr_cols = offsets + (D_OUT + 1);                                  // 512 KB
    float* csr_vals = (float*)(csr_cols + 131072);                            // 512 KB

    hipMemsetAsync(counts, 0, 2 * D_OUT * sizeof(int), stream);  // counts + cursors
    transpose_convert<<<dim3(D_OUT / 32, D_IN / 32), 256, 0, stream>>>(weight, wtb);
    convert_input<<<(N_ROWS * D_IN) / 1024, 256, 0, stream>>>(input, abf);
    count_rows<<<(E + 255) / 256, 256, 0, stream>>>(adj_rows, counts, E);
    scan_8192<<<1, 1024, 0, stream>>>(counts, offsets);
    fill_csr<<<(E + 255) / 256, 256, 0, stream>>>(adj_rows, adj_cols, adj_vals,
                                                  offsets, cursors, csr_cols, csr_vals, E);
    aggregate_rows<<<dim3(D_OUT / 4, 8), 256, 0, stream>>>(
        wtb, offsets, csr_cols, csr_vals, wpt);
    gemm_bt_bias<<<dim3(D_OUT / 128, N_ROWS / 128), 256, 0, stream>>>(
        abf, wpt, bias, (float*)d_out);
}